// Round 8
// baseline (182.249 us; speedup 1.0000x reference)
//
#include <hip/hip_runtime.h>
#include <math.h>

#define B_  2
#define S_  2048
#define E_  1024
#define H_  16
#define HD_ 64
#define N3_ 3072
#define M_  (B_*S_)   // 4096
#define NROWS_ (32 * S_)   // 65536 (bh, q) rows

typedef _Float16 h8  __attribute__((ext_vector_type(8)));
typedef _Float16 h4  __attribute__((ext_vector_type(4)));
typedef __fp16   fp16v2 __attribute__((ext_vector_type(2)));
typedef float    f4  __attribute__((ext_vector_type(4)));
typedef float    fv16 __attribute__((ext_vector_type(16)));

typedef __attribute__((address_space(3))) unsigned int       lds_u32;
typedef const __attribute__((address_space(1))) unsigned int glob_u32;

// async global->LDS, 16B/lane; global addr per-lane, LDS dest = base + lane*16.
__device__ __forceinline__ void gld16(const void* g, void* l) {
    __builtin_amdgcn_global_load_lds((glob_u32*)g, (lds_u32*)l, 16, 0, 0);
}
__device__ __forceinline__ float exp2_hw(float x) { return __builtin_amdgcn_exp2f(x); }
// pack 4 f32 -> h4 via 2x v_cvt_pkrtz_f16_f32 (builtin returns __fp16x2; bit-cast)
__device__ __forceinline__ h4 pack4(float a, float b, float c, float d) {
    union { struct { fp16v2 l, h; } p; h4 v; } u;
    u.p.l = __builtin_amdgcn_cvt_pkrtz(a, b);
    u.p.h = __builtin_amdgcn_cvt_pkrtz(c, d);
    return u.v;
}

#define QSCALE 0.18033688011112042f   // log2(e)/8

// ---------------- kernel 0b: x fp32 -> f16 ----------------
__global__ void cvt_x_kernel(const float* __restrict__ x, _Float16* __restrict__ x16) {
    int i = (blockIdx.x * 256 + threadIdx.x) * 8;
    float4 u = *(const float4*)&x[i];
    float4 v = *(const float4*)&x[i + 4];
    h8 o;
    o[0] = (_Float16)u.x; o[1] = (_Float16)u.y; o[2] = (_Float16)u.z; o[3] = (_Float16)u.w;
    o[4] = (_Float16)v.x; o[5] = (_Float16)v.y; o[6] = (_Float16)v.z; o[7] = (_Float16)v.w;
    *(h8*)&x16[i] = o;
}

// ---------------- kernel 0c: W [K][N] fp32 -> Wt [N][K] f16 ----------------
__global__ __launch_bounds__(256) void transpose_w_kernel(
        const float* __restrict__ W, _Float16* __restrict__ Wt) {
    __shared__ float T[64][65];
    int k0 = blockIdx.x * 64, n0 = blockIdx.y * 64;
    int tid = threadIdx.x;
    int r = tid >> 4, c4 = (tid & 15) * 4;
#pragma unroll
    for (int i = 0; i < 4; i++) {
        int row = r + i * 16;
        float4 u = *(const float4*)&W[(size_t)(k0 + row) * N3_ + n0 + c4];
        T[c4 + 0][row] = u.x; T[c4 + 1][row] = u.y;
        T[c4 + 2][row] = u.z; T[c4 + 3][row] = u.w;
    }
    __syncthreads();
#pragma unroll
    for (int i = 0; i < 4; i++) {
        int rn = r + i * 16;
        h4 p;
        p[0] = (_Float16)T[rn][c4 + 0]; p[1] = (_Float16)T[rn][c4 + 1];
        p[2] = (_Float16)T[rn][c4 + 2]; p[3] = (_Float16)T[rn][c4 + 3];
        *(h4*)&Wt[(size_t)(n0 + rn) * E_ + k0 + c4] = p;
    }
}

// ---------------- kernel 1: QKV GEMM, 32x32x16, 2-stage pipelined ----------
__global__ __launch_bounds__(256, 2) void qkv_gemm32(
        const _Float16* __restrict__ x16, const _Float16* __restrict__ wt,
        const float* __restrict__ bq, const float* __restrict__ w,
        _Float16* __restrict__ qws, _Float16* __restrict__ kws,
        _Float16* __restrict__ vtws) {
    __shared__ __align__(16) _Float16 Ab[2][128 * 64];   // 32 KB
    __shared__ __align__(16) _Float16 Wb[2][192 * 64];   // 48 KB

    int tid = threadIdx.x;
    int wid = tid >> 6, lane = tid & 63;
    int l31 = lane & 31, hi = lane >> 5, l7 = l31 & 7;
    int srow = lane >> 3;
    int wm = wid & 1, wn = wid >> 1;

    int L = blockIdx.x;
    int head = 2 * (L & 7) + (L >> 8);   // 2 heads per XCD
    int mb = (L >> 3) & 31;
    int m0 = mb * 128;
    int n0 = head * 192;
    int b = m0 >> 11;
    int bh = b * H_ + head;
    int sblk = m0 & 2047;

    fv16 acc[2][3];
#pragma unroll
    for (int ntl = 0; ntl < 3; ntl++) {
        int n_abs = wn * 96 + ntl * 32;
        int which = n_abs >> 6;
        fv16 ini;
        if (which == 2) {
            float bb = bq[n0 + n_abs + l31];
#pragma unroll
            for (int r = 0; r < 16; r++) ini[r] = bb;
        } else {
#pragma unroll
            for (int g = 0; g < 4; g++) {
                f4 bv = *(const f4*)&bq[n0 + n_abs + 8 * g + 4 * hi];
#pragma unroll
                for (int j = 0; j < 4; j++) ini[4 * g + j] = bv[j];
            }
        }
        acc[0][ntl] = ini; acc[1][ntl] = ini;
    }

    auto stage = [&](int t, int bf) {
        int k0 = t * 64;
#pragma unroll
        for (int j = 0; j < 4; j++) {
            int batch = wid * 4 + j;
            int row = batch * 8 + srow;
            int ch = (lane & 7) ^ srow ^ (batch & 7);
            gld16(&x16[(size_t)(m0 + row) * E_ + k0 + ch * 8], &Ab[bf][batch * 8 * 64]);
        }
#pragma unroll
        for (int j = 0; j < 6; j++) {
            int batch = wid * 6 + j;
            int row = batch * 8 + srow;
            int ch = (lane & 7) ^ srow ^ (batch & 7);
            gld16(&wt[(size_t)(n0 + row) * E_ + k0 + ch * 8], &Wb[bf][batch * 8 * 64]);
        }
    };

    stage(0, 0);

    for (int t = 0; t < 16; t++) {
        int bf = t & 1;
        __syncthreads();
        if (t < 15) stage(t + 1, bf ^ 1);
#pragma unroll
        for (int step = 0; step < 4; step++) {
            h8 af[2], wf[3];
#pragma unroll
            for (int mt = 0; mt < 2; mt++) {
                int R = wm * 64 + mt * 32 + l31;
                int ph = ((2 * step + hi) ^ l7 ^ ((mt * 4 + (l31 >> 3)) & 7)) * 8;
                af[mt] = *(const h8*)&Ab[bf][R * 64 + ph];
            }
#pragma unroll
            for (int ntl = 0; ntl < 3; ntl++) {
                int R = wn * 96 + ntl * 32 + l31;
                int ph = ((2 * step + hi) ^ l7 ^ ((wn * 12 + ntl * 4 + (l31 >> 3)) & 7)) * 8;
                wf[ntl] = *(const h8*)&Wb[bf][R * 64 + ph];
            }
#pragma unroll
            for (int ntl = 0; ntl < 3; ntl++) {
                bool isv = (wn == 1) && (ntl >= 1);
#pragma unroll
                for (int mt = 0; mt < 2; mt++) {
                    if (isv)
                        acc[mt][ntl] = __builtin_amdgcn_mfma_f32_32x32x16_f16(af[mt], wf[ntl], acc[mt][ntl], 0, 0, 0);
                    else
                        acc[mt][ntl] = __builtin_amdgcn_mfma_f32_32x32x16_f16(wf[ntl], af[mt], acc[mt][ntl], 0, 0, 0);
                }
            }
        }
    }

#pragma unroll
    for (int ntl = 0; ntl < 3; ntl++) {
        int n_abs = wn * 96 + ntl * 32;
        int which = n_abs >> 6;
#pragma unroll
        for (int mt = 0; mt < 2; mt++) {
            if (which == 2) {
                int d = (n_abs & 63) + l31;
#pragma unroll
                for (int g = 0; g < 4; g++) {
                    int soff = wm * 64 + mt * 32 + 8 * g + 4 * hi;
                    f4 wf4 = *(const f4*)&w[m0 + soff];
                    h4 p = pack4(acc[mt][ntl][4 * g + 0] * wf4[0],
                                 acc[mt][ntl][4 * g + 1] * wf4[1],
                                 acc[mt][ntl][4 * g + 2] * wf4[2],
                                 acc[mt][ntl][4 * g + 3] * wf4[3]);
                    *(h4*)&vtws[((size_t)bh * 64 + d) * S_ + sblk + soff] = p;
                }
            } else {
                _Float16* dst = (which == 0) ? qws : kws;
                float scale = (which == 0) ? QSCALE : 1.0f;
                int s = sblk + wm * 64 + mt * 32 + l31;
#pragma unroll
                for (int g = 0; g < 4; g++) {
                    int d0 = (n_abs & 63) + 8 * g + 4 * hi;
                    h4 p = pack4(acc[mt][ntl][4 * g + 0] * scale,
                                 acc[mt][ntl][4 * g + 1] * scale,
                                 acc[mt][ntl][4 * g + 2] * scale,
                                 acc[mt][ntl][4 * g + 3] * scale);
                    *(h4*)&dst[((size_t)bh * S_ + s) * 64 + d0] = p;
                }
            }
        }
    }
}

// ---------------- kernel 2: flash attention, K-split by 2 ----------------
// Grid 1024: bh = (L&7)+8*(L>>8), qt = (L>>3)&15, half = (L>>7)&1.
// Each block: 128 q x 1024 keys (16 iters). Partial O self-normalized (f16)
// + (m,l) f32 to ws; combine kernel merges halves.
__global__ __launch_bounds__(256, 2) void attn_kernel(
        const _Float16* __restrict__ q, const _Float16* __restrict__ k,
        const _Float16* __restrict__ vt, const float* __restrict__ w,
        _Float16* __restrict__ opart, float* __restrict__ ml) {
    __shared__ __align__(16) _Float16 Kb[2][64 * 64];   // 16 KB
    __shared__ __align__(16) _Float16 Vb[2][64 * 64];   // 16 KB
    __shared__ __align__(16) float lws[1024];           //  4 KB: w half-row

    int tid = threadIdx.x;
    int wid = tid >> 6, lane = tid & 63;
    int l31 = lane & 31, hi = lane >> 5, l7 = l31 & 7;
    int srow = lane >> 3;
    int L = blockIdx.x;
    int bh = (L & 7) + 8 * (L >> 8);    // bh pinned per XCD
    int qt = (L >> 3) & 15;
    int half = (L >> 7) & 1;
    int q0 = qt * 128;
    int kh0 = half * 1024;
    int b = bh >> 4;

    const _Float16* qbase = q + (size_t)bh * S_ * HD_;
    const _Float16* kbase = k + (size_t)bh * S_ * HD_;
    const _Float16* vbase = vt + (size_t)bh * HD_ * S_;
    const float* wbase = w + (size_t)b * S_;

    // stage w half-row (fp32, 4 KB, 1 batch of 1 KB per wave)
    gld16(&wbase[kh0 + wid * 256 + lane * 4], &lws[wid * 256]);

    auto stage = [&](int kt, int bf) {
        int k0 = kh0 + kt * 64;
#pragma unroll
        for (int j = 0; j < 2; j++) {
            int batch = wid * 2 + j;
            int row = batch * 8 + srow;
            int ch = (lane & 7) ^ srow ^ (batch & 7);
            gld16(&kbase[(size_t)(k0 + row) * 64 + ch * 8], &Kb[bf][batch * 8 * 64]);
            gld16(&vbase[(size_t)row * S_ + k0 + ch * 8], &Vb[bf][batch * 8 * 64]);
        }
    };

    stage(0, 0);

    int qrow = q0 + wid * 32 + l31;
    h8 qf[4];
#pragma unroll
    for (int step = 0; step < 4; step++)
        qf[step] = *(const h8*)&qbase[(size_t)qrow * 64 + 16 * step + 8 * hi];

    fv16 o[2];
    o[0] = (fv16)0.0f; o[1] = (fv16)0.0f;
    float m_r = -INFINITY, l_r = 0.0f;

    for (int kt = 0; kt < 16; kt++) {
        int bf = kt & 1;
        __syncthreads();
        if (kt < 15) stage(kt + 1, bf ^ 1);

        // ---- S^T = K*Q^T : rows k, cols q=l31 ----
        fv16 st[2];
        st[0] = (fv16)0.0f; st[1] = (fv16)0.0f;
#pragma unroll
        for (int step = 0; step < 4; step++) {
#pragma unroll
            for (int kt2 = 0; kt2 < 2; kt2++) {
                int R = kt2 * 32 + l31;
                int ph = ((2 * step + hi) ^ l7 ^ ((kt2 * 4 + (l31 >> 3)) & 7)) * 8;
                h8 kf = *(const h8*)&Kb[bf][R * 64 + ph];
                st[kt2] = __builtin_amdgcn_mfma_f32_32x32x16_f16(kf, qf[step], st[kt2], 0, 0, 0);
            }
        }

        // ---- online softmax (base 2), lane-local state (q = l31) ----
        float rm = -INFINITY;
#pragma unroll
        for (int kt2 = 0; kt2 < 2; kt2++)
#pragma unroll
            for (int r = 0; r < 16; r++) rm = fmaxf(rm, st[kt2][r]);
        rm = fmaxf(rm, __shfl_xor(rm, 32));
        float mnew = fmaxf(m_r, rm);
        float rs = 0.0f;
        h4 pf[2][4];
        int kk = kt * 64;
#pragma unroll
        for (int kt2 = 0; kt2 < 2; kt2++)
#pragma unroll
            for (int g = 0; g < 4; g++) {
                f4 wv = *(const f4*)&lws[kk + kt2 * 32 + 8 * g + 4 * hi];
                float e0 = exp2_hw(st[kt2][4 * g + 0] - mnew);
                float e1 = exp2_hw(st[kt2][4 * g + 1] - mnew);
                float e2 = exp2_hw(st[kt2][4 * g + 2] - mnew);
                float e3 = exp2_hw(st[kt2][4 * g + 3] - mnew);
                rs = fmaf(e0, wv[0], rs); rs = fmaf(e1, wv[1], rs);
                rs = fmaf(e2, wv[2], rs); rs = fmaf(e3, wv[3], rs);
                pf[kt2][g] = pack4(e0, e1, e2, e3);
            }
        rs += __shfl_xor(rs, 32);
        float alpha = exp2_hw(m_r - mnew);
        m_r = mnew;
        l_r = l_r * alpha + rs;
        o[0] = o[0] * alpha;
        o[1] = o[1] * alpha;

        // ---- O^T += V'^T * P (32x32x8: B k-stripe matches C regs) ----
#pragma unroll
        for (int kt2 = 0; kt2 < 2; kt2++)
#pragma unroll
            for (int g = 0; g < 4; g++) {
                int c = 4 * kt2 + g;
#pragma unroll
                for (int dt = 0; dt < 2; dt++) {
                    int R = dt * 32 + l31;
                    int ph = (c ^ l7 ^ ((dt * 4 + (l31 >> 3)) & 7)) * 8 + hi * 4;
                    h4 vf = *(const h4*)&Vb[bf][R * 64 + ph];
                    o[dt] = __builtin_amdgcn_mfma_f32_32x32x8f16(vf, pf[kt2][g], o[dt], 0, 0, 0);
                }
            }
    }

    // ---- epilogue: self-normalized partial -> opart (f16), (m,l) -> ml ----
    size_t prow = (size_t)(half * 32 + bh) * S_ + qrow;
    float linv = 1.0f / l_r;
    _Float16* obase = &opart[prow * 64];
#pragma unroll
    for (int dt = 0; dt < 2; dt++)
#pragma unroll
        for (int g = 0; g < 4; g++) {
            int d0 = dt * 32 + 8 * g + 4 * hi;
            h4 p = pack4(o[dt][4 * g + 0] * linv, o[dt][4 * g + 1] * linv,
                         o[dt][4 * g + 2] * linv, o[dt][4 * g + 3] * linv);
            *(h4*)&obase[d0] = p;
        }
    if (hi == 0) {
        float2 v; v.x = m_r; v.y = l_r;
        *(float2*)&ml[prow * 2] = v;
    }
}

// ---------------- kernel 3: combine the two K-halves ----------------
__global__ __launch_bounds__(256) void combine_kernel(
        const _Float16* __restrict__ opart, const float* __restrict__ ml,
        float* __restrict__ out) {
    int t = threadIdx.x;
    int r = blockIdx.x * 64 + (t >> 2);   // row 0..65535 = bh*2048 + qrow
    int dg = (t & 3) * 16;
    int bh = r >> 11, qrow = r & 2047;
    float2 ml0 = *(const float2*)&ml[(size_t)r * 2];
    float2 ml1 = *(const float2*)&ml[((size_t)NROWS_ + r) * 2];
    float Mx = fmaxf(ml0.x, ml1.x);
    float w0 = ml0.y * exp2_hw(ml0.x - Mx);
    float w1 = ml1.y * exp2_hw(ml1.x - Mx);
    float inv = 1.0f / (w0 + w1);
    w0 *= inv; w1 *= inv;
    const _Float16* o0 = &opart[(size_t)r * 64 + dg];
    const _Float16* o1 = &opart[((size_t)NROWS_ + r) * 64 + dg];
    float* ob = &out[((size_t)((bh >> 4) * S_ + qrow)) * E_ + (bh & 15) * 64 + dg];
#pragma unroll
    for (int i = 0; i < 2; i++) {
        h8 a = *(const h8*)&o0[i * 8];
        h8 c = *(const h8*)&o1[i * 8];
        f4 r0, r1;
#pragma unroll
        for (int j = 0; j < 4; j++) {
            r0[j] = (float)a[j] * w0 + (float)c[j] * w1;
            r1[j] = (float)a[4 + j] * w0 + (float)c[4 + j] * w1;
        }
        *(f4*)&ob[i * 8] = r0;
        *(f4*)&ob[i * 8 + 4] = r1;
    }
}

extern "C" void kernel_launch(void* const* d_in, const int* in_sizes, int n_in,
                              void* d_out, int out_size, void* d_ws, size_t ws_size,
                              hipStream_t stream) {
    const float* x  = (const float*)d_in[0];
    const float* w  = (const float*)d_in[1];
    const float* Wq = (const float*)d_in[2];
    const float* bq = (const float*)d_in[3];
    float* out = (float*)d_out;

    // ws: x16 8MB | wt 6MB | q 8MB | k 8MB | vt 8MB | opart 16MB | ml 1MB = 55MB
    char* p = (char*)d_ws;
    _Float16* x16 = (_Float16*)p;              p += (size_t)M_ * E_ * 2;
    _Float16* wt  = (_Float16*)p;              p += (size_t)E_ * N3_ * 2;
    _Float16* qb  = (_Float16*)p;              p += (size_t)M_ * E_ * 2;
    _Float16* kb  = (_Float16*)p;              p += (size_t)M_ * E_ * 2;
    _Float16* vtb = (_Float16*)p;              p += (size_t)M_ * E_ * 2;
    _Float16* opart = (_Float16*)p;            p += (size_t)2 * NROWS_ * 64 * 2;
    float* mlb = (float*)p;

    cvt_x_kernel<<<dim3(M_ * E_ / 2048), dim3(256), 0, stream>>>(x, x16);
    transpose_w_kernel<<<dim3(E_ / 64, N3_ / 64), dim3(256), 0, stream>>>(Wq, wt);
    qkv_gemm32<<<dim3(512), dim3(256), 0, stream>>>(x16, wt, bq, w, qb, kb, vtb);
    attn_kernel<<<dim3(1024), dim3(256), 0, stream>>>(qb, kb, vtb, w, opart, mlb);
    combine_kernel<<<dim3(NROWS_ / 64), dim3(256), 0, stream>>>(opart, mlb, out);
}